// Round 1
// baseline (33193.082 us; speedup 1.0000x reference)
//
#include <hip/hip_runtime.h>
#include <math.h>

// ---------------- problem constants ----------------
#define N_AUTHOR 100000
#define N_FOS    30000
#define N_INST   8000
#define N_PAPER  150000
#define N_TOTAL  288000
#define NEDGE    500000
// row offsets in NODE_ORDER = [author, fos, inst, paper]
#define OFF_AUTHOR 0
#define OFF_FOS    100000
#define OFF_INST   130000
#define OFF_PAPER  138000

// ---------------- helpers ----------------
__device__ inline void atomicMaxF(float* addr, float v) {
    // sign-aware int trick; buffer initialized to -inf
    if (v >= 0.0f) atomicMax((int*)addr, __float_as_int(v));
    else           atomicMin((unsigned int*)addr, __float_as_uint(v));
}

// ---------------- generic tiled SGEMM: C = A[N,256] @ B[256,M] (+bias) ----------------
// block 256 threads, tile 64 rows x 64 cols, each thread 4x4
template<bool HAS_BIAS>
__global__ void sgemm_k256(const float* __restrict__ A, const float* __restrict__ B,
                           const float* __restrict__ bias, float* __restrict__ C,
                           int N, int M) {
    __shared__ float As[64][17];
    __shared__ float Bs[16][64];
    const int tid = threadIdx.x;
    const int tx = tid & 15, ty = tid >> 4;
    const int rowBase = blockIdx.x * 64;
    const int colBase = blockIdx.y * 64;
    float acc[4][4] = {};
    for (int k0 = 0; k0 < 256; k0 += 16) {
#pragma unroll
        for (int s = 0; s < 4; ++s) {
            int l = tid + s * 256;
            int r = l >> 4, k = l & 15;
            int row = rowBase + r;
            As[r][k] = (row < N) ? A[(size_t)row * 256 + k0 + k] : 0.0f;
        }
#pragma unroll
        for (int s = 0; s < 4; ++s) {
            int l = tid + s * 256;
            int kk = l >> 6, c = l & 63;
            Bs[kk][c] = B[(size_t)(k0 + kk) * M + colBase + c];
        }
        __syncthreads();
#pragma unroll
        for (int kk = 0; kk < 16; ++kk) {
            float a[4], b[4];
#pragma unroll
            for (int i = 0; i < 4; ++i) a[i] = As[ty + i * 16][kk];
#pragma unroll
            for (int j = 0; j < 4; ++j) b[j] = Bs[kk][tx + j * 16];
#pragma unroll
            for (int i = 0; i < 4; ++i)
#pragma unroll
                for (int j = 0; j < 4; ++j)
                    acc[i][j] += a[i] * b[j];
        }
        __syncthreads();
    }
#pragma unroll
    for (int i = 0; i < 4; ++i) {
        int row = rowBase + ty + i * 16;
        if (row < N) {
#pragma unroll
            for (int j = 0; j < 4; ++j) {
                int col = colBase + tx + j * 16;
                float v = acc[i][j];
                if (HAS_BIAS) v += bias[col];
                C[(size_t)row * M + col] = v;
            }
        }
    }
}

// ---------------- init sum/max/cnt per relation ----------------
__global__ void init_agg(float* __restrict__ sumb, float* __restrict__ maxb,
                         int* __restrict__ cnt, int n) {
    size_t i = (size_t)blockIdx.x * 256 + threadIdx.x;
    size_t tot = (size_t)n * 256;
    if (i < tot) { sumb[i] = 0.0f; maxb[i] = -INFINITY; }
    if (i < (size_t)n) cnt[i] = 0;
}

// ---------------- edge scatter: one 64-lane wave per edge ----------------
__global__ void scatter_edges(const float* __restrict__ bases_src,
                              const int* __restrict__ src, const int* __restrict__ dst,
                              float* __restrict__ sumb, float* __restrict__ maxb,
                              int* __restrict__ cnt, int ne) {
    int e = blockIdx.x * 4 + (threadIdx.x >> 6);
    if (e >= ne) return;
    int lane = threadIdx.x & 63;
    int s = src[e], d = dst[e];
    const float4 v = ((const float4*)(bases_src + (size_t)s * 256))[lane];
    size_t base = (size_t)d * 256 + (size_t)lane * 4;
    atomicAdd(sumb + base + 0, v.x);
    atomicAdd(sumb + base + 1, v.y);
    atomicAdd(sumb + base + 2, v.z);
    atomicAdd(sumb + base + 3, v.w);
    atomicMaxF(maxb + base + 0, v.x);
    atomicMaxF(maxb + base + 1, v.y);
    atomicMaxF(maxb + base + 2, v.z);
    atomicMaxF(maxb + base + 3, v.w);
    if (lane == 0) atomicAdd(cnt + d, 1);
}

// ---------------- root combine: out[n,h,d] = sum_k w[n,h*8+k] * bases[n,k*32+d] ----------------
__global__ void root_combine(const float* __restrict__ w, const float* __restrict__ bases,
                             float* __restrict__ out, int n) {
    size_t i = (size_t)blockIdx.x * 256 + threadIdx.x;
    size_t tot = (size_t)n * 256;
    if (i >= tot) return;
    int node = (int)(i >> 8);
    int col = (int)(i & 255);
    int h = col >> 5, dch = col & 31;
    const float* wr = w + (size_t)node * 64 + h * 8;
    const float* br = bases + (size_t)node * 256 + dch;
    float acc = 0.0f;
#pragma unroll
    for (int k = 0; k < 8; ++k) acc += wr[k] * br[k * 32];
    out[i] = acc;
}

// ---------------- relation combine: out += einsum(w, [mean; max]) ----------------
__global__ void rel_combine(const float* __restrict__ w, const float* __restrict__ sumb,
                            const float* __restrict__ maxb, const int* __restrict__ cnt,
                            float* __restrict__ out, int n) {
    size_t i = (size_t)blockIdx.x * 256 + threadIdx.x;
    size_t tot = (size_t)n * 256;
    if (i >= tot) return;
    int node = (int)(i >> 8);
    int col = (int)(i & 255);
    int h = col >> 5, dch = col & 31;
    float c = (float)cnt[node];
    float inv = 1.0f / fmaxf(c, 1.0f);
    const float* wr = w + (size_t)node * 128 + h * 16;
    const float* sr = sumb + (size_t)node * 256 + dch;
    const float* mr = maxb + (size_t)node * 256 + dch;
    float acc = 0.0f;
#pragma unroll
    for (int k = 0; k < 8; ++k) {
        acc += wr[k] * (sr[k * 32] * inv);
        float m = mr[k * 32];
        m = isfinite(m) ? m : 0.0f;
        acc += wr[8 + k] * m;
    }
    out[i] += acc;
}

// ---------------- host launcher ----------------
extern "C" void kernel_launch(void* const* d_in, const int* in_sizes, int n_in,
                              void* d_out, int out_size, void* d_ws, size_t ws_size,
                              hipStream_t stream) {
    (void)in_sizes; (void)n_in; (void)out_size; (void)ws_size;

    const float* xs[4]  = { (const float*)d_in[0], (const float*)d_in[1],
                            (const float*)d_in[2], (const float*)d_in[3] };
    const int   nn[4]   = { N_AUTHOR, N_FOS, N_INST, N_PAPER };
    const int   off[4]  = { OFF_AUTHOR, OFF_FOS, OFF_INST, OFF_PAPER };

    const float* W_bases = (const float*)d_in[18];

    // workspace layout (floats)
    float* bases = (float*)d_ws;                           // N_TOTAL*256
    float* sumb  = bases + (size_t)N_TOTAL * 256;          // 150000*256
    float* maxb  = sumb + (size_t)N_PAPER * 256;           // 150000*256
    int*   cnt   = (int*)(maxb + (size_t)N_PAPER * 256);   // 150000 (+pad)
    float* wbuf  = (float*)(cnt + 150016);                 // 150000*128

    float* out = (float*)d_out;

    // 1. bases = x @ W_bases for each node type
    for (int t = 0; t < 4; ++t) {
        dim3 grid((nn[t] + 63) / 64, 4);
        sgemm_k256<false><<<grid, 256, 0, stream>>>(
            xs[t], W_bases, nullptr, bases + (size_t)off[t] * 256, nn[t], 256);
    }

    // 2. root path (initializes d_out)
    const int rootWi[4] = {33, 35, 37, 39};
    for (int t = 0; t < 4; ++t) {
        dim3 grid((nn[t] + 63) / 64, 1);
        sgemm_k256<true><<<grid, 256, 0, stream>>>(
            xs[t], (const float*)d_in[rootWi[t]], (const float*)d_in[rootWi[t] + 1],
            wbuf, nn[t], 64);
        int nb = (int)(((size_t)nn[t] * 256 + 255) / 256);
        root_combine<<<nb, 256, 0, stream>>>(
            wbuf, bases + (size_t)off[t] * 256, out + (size_t)off[t] * 256, nn[t]);
    }

    // 3. relations: {src_in, dst_in, st, dt, relW_in}
    const int rel[7][5] = {
        {4, 5, 0, 2, 19},   // a_i: author -> inst
        {6, 7, 2, 0, 21},   // i_a: inst -> author
        {8, 9, 0, 3, 23},   // a_p: author -> paper
        {10, 11, 3, 0, 25}, // p_a: paper -> author
        {12, 13, 3, 3, 27}, // p_p: paper -> paper
        {14, 15, 3, 1, 29}, // p_f: paper -> fos
        {16, 17, 1, 3, 31}, // f_p: fos -> paper
    };
    for (int r = 0; r < 7; ++r) {
        int st = rel[r][2], dt = rel[r][3];
        int ndt = nn[dt];
        int nb = (int)(((size_t)ndt * 256 + 255) / 256);
        init_agg<<<nb, 256, 0, stream>>>(sumb, maxb, cnt, ndt);
        scatter_edges<<<(NEDGE + 3) / 4, 256, 0, stream>>>(
            bases + (size_t)off[st] * 256,
            (const int*)d_in[rel[r][0]], (const int*)d_in[rel[r][1]],
            sumb, maxb, cnt, NEDGE);
        dim3 grid((ndt + 63) / 64, 2);
        sgemm_k256<true><<<grid, 256, 0, stream>>>(
            xs[dt], (const float*)d_in[rel[r][4]], (const float*)d_in[rel[r][4] + 1],
            wbuf, ndt, 128);
        rel_combine<<<nb, 256, 0, stream>>>(
            wbuf, sumb, maxb, cnt, out + (size_t)off[dt] * 256, ndt);
    }
}

// Round 2
// 4216.881 us; speedup vs baseline: 7.8715x; 7.8715x over previous
//
#include <hip/hip_runtime.h>
#include <math.h>

// ---------------- problem constants ----------------
#define N_AUTHOR 100000
#define N_FOS    30000
#define N_INST   8000
#define N_PAPER  150000
#define N_TOTAL  288000
#define NEDGE    500000
// row offsets in NODE_ORDER = [author, fos, inst, paper]
#define OFF_AUTHOR 0
#define OFF_FOS    100000
#define OFF_INST   130000
#define OFF_PAPER  138000
#define MAXN 150016   // padded max node count for int buffers

// ---------------- generic tiled SGEMM: C = A[N,256] @ B[256,M] (+bias) ----------------
// block 256 threads, tile 64 rows x 64 cols, each thread 4x4
template<bool HAS_BIAS>
__global__ void sgemm_k256(const float* __restrict__ A, const float* __restrict__ B,
                           const float* __restrict__ bias, float* __restrict__ C,
                           int N, int M) {
    __shared__ float As[64][17];
    __shared__ float Bs[16][64];
    const int tid = threadIdx.x;
    const int tx = tid & 15, ty = tid >> 4;
    const int rowBase = blockIdx.x * 64;
    const int colBase = blockIdx.y * 64;
    float acc[4][4] = {};
    for (int k0 = 0; k0 < 256; k0 += 16) {
#pragma unroll
        for (int s = 0; s < 4; ++s) {
            int l = tid + s * 256;
            int r = l >> 4, k = l & 15;
            int row = rowBase + r;
            As[r][k] = (row < N) ? A[(size_t)row * 256 + k0 + k] : 0.0f;
        }
#pragma unroll
        for (int s = 0; s < 4; ++s) {
            int l = tid + s * 256;
            int kk = l >> 6, c = l & 63;
            Bs[kk][c] = B[(size_t)(k0 + kk) * M + colBase + c];
        }
        __syncthreads();
#pragma unroll
        for (int kk = 0; kk < 16; ++kk) {
            float a[4], b[4];
#pragma unroll
            for (int i = 0; i < 4; ++i) a[i] = As[ty + i * 16][kk];
#pragma unroll
            for (int j = 0; j < 4; ++j) b[j] = Bs[kk][tx + j * 16];
#pragma unroll
            for (int i = 0; i < 4; ++i)
#pragma unroll
                for (int j = 0; j < 4; ++j)
                    acc[i][j] += a[i] * b[j];
        }
        __syncthreads();
    }
#pragma unroll
    for (int i = 0; i < 4; ++i) {
        int row = rowBase + ty + i * 16;
        if (row < N) {
#pragma unroll
            for (int j = 0; j < 4; ++j) {
                int col = colBase + tx + j * 16;
                float v = acc[i][j];
                if (HAS_BIAS) v += bias[col];
                C[(size_t)row * M + col] = v;
            }
        }
    }
}

// ---------------- CSR build ----------------
__global__ void zero_cnt(int* __restrict__ cnt, int n) {
    int i = blockIdx.x * 256 + threadIdx.x;
    if (i < n) cnt[i] = 0;
}

__global__ void histogram(const int* __restrict__ dst, int* __restrict__ cnt, int ne) {
    int e = blockIdx.x * 256 + threadIdx.x;
    if (e < ne) atomicAdd(cnt + dst[e], 1);
}

// block-wise inclusive scan of cnt -> incl, blocksum[b] = block total
__global__ void scan1(const int* __restrict__ cnt, int* __restrict__ incl,
                      int* __restrict__ blocksum, int n) {
    __shared__ int s[256];
    int t = threadIdx.x;
    int i = blockIdx.x * 256 + t;
    int v = (i < n) ? cnt[i] : 0;
    s[t] = v;
    __syncthreads();
#pragma unroll
    for (int off = 1; off < 256; off <<= 1) {
        int add = (t >= off) ? s[t - off] : 0;
        __syncthreads();
        s[t] += add;
        __syncthreads();
    }
    if (i < n) incl[i] = s[t];
    if (t == 255) blocksum[blockIdx.x] = s[255];
}

// single block: exclusive scan of blocksum (nb <= 1024)
__global__ void scan2(int* __restrict__ blocksum, int nb) {
    __shared__ int s[1024];
    int t = threadIdx.x;
    int v = (t < nb) ? blocksum[t] : 0;
    s[t] = v;
    __syncthreads();
#pragma unroll
    for (int off = 1; off < 1024; off <<= 1) {
        int add = (t >= off) ? s[t - off] : 0;
        __syncthreads();
        s[t] += add;
        __syncthreads();
    }
    if (t < nb) blocksum[t] = s[t] - v;   // exclusive
}

// cursor[i] = exclusive prefix of cnt = incl[i] - cnt[i] + blockoff
__global__ void scan3(const int* __restrict__ cnt, const int* __restrict__ incl,
                      const int* __restrict__ blocksum, int* __restrict__ cursor, int n) {
    int i = blockIdx.x * 256 + threadIdx.x;
    if (i < n) cursor[i] = incl[i] - cnt[i] + blocksum[blockIdx.x];
}

// fill: srcidx[slot] = src[e], slot allocated via cursor atomic
__global__ void fill_csr(const int* __restrict__ src, const int* __restrict__ dst,
                         int* __restrict__ cursor, int* __restrict__ srcidx, int ne) {
    int e = blockIdx.x * 256 + threadIdx.x;
    if (e < ne) {
        int pos = atomicAdd(cursor + dst[e], 1);
        srcidx[pos] = src[e];
    }
}

// ---------------- gather + reduce + fused combine ----------------
// one 64-lane wave per destination node; 4 waves (4 nodes) per block.
// after fill_csr, cursor[i] = end of node i's list; start = end - cnt[i].
// w[node,128] = x_dt @ relW + relb (precomputed in wbuf).
// out[node,256] += einsum over [mean(8 bases); max(8 bases)] x DPH=32.
__global__ void gather_combine(const float* __restrict__ bases_src,
                               const int* __restrict__ srcidx,
                               const int* __restrict__ cursor,
                               const int* __restrict__ cnt,
                               const float* __restrict__ w,
                               float* __restrict__ out, int ndt) {
    __shared__ float lds[4][512];   // per wave: [0..255]=mean, [256..511]=max
    const int wv = threadIdx.x >> 6;
    const int lane = threadIdx.x & 63;
    const int node = blockIdx.x * 4 + wv;
    const bool active = node < ndt;

    if (active) {
        int deg = cnt[node];
        int start = cursor[node] - deg;
        float4 s = make_float4(0.f, 0.f, 0.f, 0.f);
        float4 m = make_float4(-INFINITY, -INFINITY, -INFINITY, -INFINITY);
        for (int i = 0; i < deg; ++i) {
            int sidx = srcidx[start + i];
            const float4 v = ((const float4*)(bases_src + (size_t)sidx * 256))[lane];
            s.x += v.x; s.y += v.y; s.z += v.z; s.w += v.w;
            m.x = fmaxf(m.x, v.x); m.y = fmaxf(m.y, v.y);
            m.z = fmaxf(m.z, v.z); m.w = fmaxf(m.w, v.w);
        }
        float inv = 1.0f / fmaxf((float)deg, 1.0f);
        float4 mean = make_float4(s.x * inv, s.y * inv, s.z * inv, s.w * inv);
        m.x = isfinite(m.x) ? m.x : 0.0f;
        m.y = isfinite(m.y) ? m.y : 0.0f;
        m.z = isfinite(m.z) ? m.z : 0.0f;
        m.w = isfinite(m.w) ? m.w : 0.0f;
        ((float4*)(lds[wv]))[lane] = mean;
        ((float4*)(lds[wv] + 256))[lane] = m;
    }
    __syncthreads();
    if (active) {
        const float* wr = w + (size_t)node * 128;
        float* outr = out + (size_t)node * 256;
#pragma unroll
        for (int j = 0; j < 4; ++j) {
            int col = j * 64 + lane;       // dch = lane&31 -> conflict-free LDS banks
            int h = col >> 5, dch = col & 31;
            const float* wh = wr + h * 16;
            float acc = 0.0f;
#pragma unroll
            for (int k = 0; k < 8; ++k) {
                acc += wh[k] * lds[wv][k * 32 + dch];             // mean part
                acc += wh[8 + k] * lds[wv][256 + k * 32 + dch];   // max part
            }
            outr[col] += acc;
        }
    }
}

// ---------------- root combine: out[n,h,d] = sum_k w[n,h*8+k] * bases[n,k*32+d] ----------------
__global__ void root_combine(const float* __restrict__ w, const float* __restrict__ bases,
                             float* __restrict__ out, int n) {
    size_t i = (size_t)blockIdx.x * 256 + threadIdx.x;
    size_t tot = (size_t)n * 256;
    if (i >= tot) return;
    int node = (int)(i >> 8);
    int col = (int)(i & 255);
    int h = col >> 5, dch = col & 31;
    const float* wr = w + (size_t)node * 64 + h * 8;
    const float* br = bases + (size_t)node * 256 + dch;
    float acc = 0.0f;
#pragma unroll
    for (int k = 0; k < 8; ++k) acc += wr[k] * br[k * 32];
    out[i] = acc;
}

// ---------------- host launcher ----------------
extern "C" void kernel_launch(void* const* d_in, const int* in_sizes, int n_in,
                              void* d_out, int out_size, void* d_ws, size_t ws_size,
                              hipStream_t stream) {
    (void)in_sizes; (void)n_in; (void)out_size; (void)ws_size;

    const float* xs[4]  = { (const float*)d_in[0], (const float*)d_in[1],
                            (const float*)d_in[2], (const float*)d_in[3] };
    const int   nn[4]   = { N_AUTHOR, N_FOS, N_INST, N_PAPER };
    const int   off[4]  = { OFF_AUTHOR, OFF_FOS, OFF_INST, OFF_PAPER };

    const float* W_bases = (const float*)d_in[18];

    // workspace layout
    float* bases   = (float*)d_ws;                          // N_TOTAL*256 f32
    float* wbuf    = bases + (size_t)N_TOTAL * 256;         // 150000*128 f32
    int*   cnt     = (int*)(wbuf + (size_t)N_PAPER * 128);  // MAXN
    int*   incl    = cnt + MAXN;                            // MAXN
    int*   cursor  = incl + MAXN;                           // MAXN
    int*   blocksum= cursor + MAXN;                         // 1024
    int*   srcidx  = blocksum + 1024;                       // NEDGE

    float* out = (float*)d_out;

    // 1. bases = x @ W_bases for each node type
    for (int t = 0; t < 4; ++t) {
        dim3 grid((nn[t] + 63) / 64, 4);
        sgemm_k256<false><<<grid, 256, 0, stream>>>(
            xs[t], W_bases, nullptr, bases + (size_t)off[t] * 256, nn[t], 256);
    }

    // 2. root path (initializes d_out)
    const int rootWi[4] = {33, 35, 37, 39};
    for (int t = 0; t < 4; ++t) {
        dim3 grid((nn[t] + 63) / 64, 1);
        sgemm_k256<true><<<grid, 256, 0, stream>>>(
            xs[t], (const float*)d_in[rootWi[t]], (const float*)d_in[rootWi[t] + 1],
            wbuf, nn[t], 64);
        int nb = (int)(((size_t)nn[t] * 256 + 255) / 256);
        root_combine<<<nb, 256, 0, stream>>>(
            wbuf, bases + (size_t)off[t] * 256, out + (size_t)off[t] * 256, nn[t]);
    }

    // 3. relations: {src_in, dst_in, st, dt, relW_in}
    const int rel[7][5] = {
        {4, 5, 0, 2, 19},   // a_i: author -> inst
        {6, 7, 2, 0, 21},   // i_a: inst -> author
        {8, 9, 0, 3, 23},   // a_p: author -> paper
        {10, 11, 3, 0, 25}, // p_a: paper -> author
        {12, 13, 3, 3, 27}, // p_p: paper -> paper
        {14, 15, 3, 1, 29}, // p_f: paper -> fos
        {16, 17, 1, 3, 31}, // f_p: fos -> paper
    };
    const int eb = (NEDGE + 255) / 256;
    for (int r = 0; r < 7; ++r) {
        int st = rel[r][2], dt = rel[r][3];
        int ndt = nn[dt];
        const int* srcp = (const int*)d_in[rel[r][0]];
        const int* dstp = (const int*)d_in[rel[r][1]];
        int nb256 = (ndt + 255) / 256;

        // CSR build
        zero_cnt<<<nb256, 256, 0, stream>>>(cnt, ndt);
        histogram<<<eb, 256, 0, stream>>>(dstp, cnt, NEDGE);
        scan1<<<nb256, 256, 0, stream>>>(cnt, incl, blocksum, ndt);
        scan2<<<1, 1024, 0, stream>>>(blocksum, nb256);
        scan3<<<nb256, 256, 0, stream>>>(cnt, incl, blocksum, cursor, ndt);
        fill_csr<<<eb, 256, 0, stream>>>(srcp, dstp, cursor, srcidx, NEDGE);

        // w = x_dt @ relW + relb
        dim3 grid((ndt + 63) / 64, 2);
        sgemm_k256<true><<<grid, 256, 0, stream>>>(
            xs[dt], (const float*)d_in[rel[r][4]], (const float*)d_in[rel[r][4] + 1],
            wbuf, ndt, 128);

        // gather + reduce + combine (fused)
        gather_combine<<<(ndt + 3) / 4, 256, 0, stream>>>(
            bases + (size_t)off[st] * 256, srcidx, cursor, cnt,
            wbuf, out + (size_t)off[dt] * 256, ndt);
    }
}